// Round 1
// baseline (1037.511 us; speedup 1.0000x reference)
//
#include <hip/hip_runtime.h>
#include <hip/hip_bf16.h>

#define N_USERS 100000
#define N_ITEMS 50000
#define N_NODES 150000
#define DIM 64
#define N_EDGES 4000000
#define BATCH 4096
#define SCAN_CHUNK 1024
#define SCAN_NBLK ((N_NODES + SCAN_CHUNK - 1) / SCAN_CHUNK)  // 147

// ---------------- CSR build ----------------

__global__ void k_hist(const int* __restrict__ dst, int* __restrict__ deg) {
    int i = blockIdx.x * blockDim.x + threadIdx.x;
    int stride = gridDim.x * blockDim.x;
    for (; i < N_EDGES; i += stride) atomicAdd(&deg[dst[i]], 1);
}

// block partial sums over 1024-element chunks
__global__ void k_scan1(const int* __restrict__ deg, int* __restrict__ partial) {
    __shared__ int waveS[4];
    int t = threadIdx.x;
    int base = blockIdx.x * SCAN_CHUNK + t * 4;
    int sum = 0;
#pragma unroll
    for (int j = 0; j < 4; j++) {
        int idx = base + j;
        if (idx < N_NODES) sum += deg[idx];
    }
    for (int off = 32; off; off >>= 1) sum += __shfl_down(sum, off);
    int lane = t & 63, w = t >> 6;
    if (lane == 0) waveS[w] = sum;
    __syncthreads();
    if (t == 0) partial[blockIdx.x] = waveS[0] + waveS[1] + waveS[2] + waveS[3];
}

// single-wave exclusive scan of partials (in place)
__global__ void k_scan2(int* __restrict__ partial) {
    int lane = threadIdx.x;  // blockDim = 64
    int carry = 0;
    for (int base = 0; base < SCAN_NBLK; base += 64) {
        int i = base + lane;
        int x = (i < SCAN_NBLK) ? partial[i] : 0;
        int incl = x;
        for (int off = 1; off < 64; off <<= 1) {
            int y = __shfl_up(incl, off);
            if (lane >= off) incl += y;
        }
        if (i < SCAN_NBLK) partial[i] = carry + incl - x;  // exclusive
        carry += __shfl(incl, 63);
    }
}

// per-chunk exclusive scan + partial offset -> row_ptr
__global__ void k_scan3(const int* __restrict__ deg, const int* __restrict__ partial,
                        int* __restrict__ row_ptr) {
    __shared__ int waveS[4];
    int t = threadIdx.x;
    int base = blockIdx.x * SCAN_CHUNK + t * 4;
    int x0 = (base + 0 < N_NODES) ? deg[base + 0] : 0;
    int x1 = (base + 1 < N_NODES) ? deg[base + 1] : 0;
    int x2 = (base + 2 < N_NODES) ? deg[base + 2] : 0;
    int x3 = (base + 3 < N_NODES) ? deg[base + 3] : 0;
    int tsum = x0 + x1 + x2 + x3;
    int lane = t & 63, w = t >> 6;
    int incl = tsum;
    for (int off = 1; off < 64; off <<= 1) {
        int y = __shfl_up(incl, off);
        if (lane >= off) incl += y;
    }
    if (lane == 63) waveS[w] = incl;
    __syncthreads();
    int woff = 0;
    for (int j = 0; j < w; j++) woff += waveS[j];
    int excl = incl - tsum + woff + partial[blockIdx.x];
    if (base + 0 < N_NODES) row_ptr[base + 0] = excl;
    if (base + 1 < N_NODES) row_ptr[base + 1] = excl + x0;
    if (base + 2 < N_NODES) row_ptr[base + 2] = excl + x0 + x1;
    if (base + 3 < N_NODES) row_ptr[base + 3] = excl + x0 + x1 + x2;
    if (blockIdx.x == 0 && t == 0) row_ptr[N_NODES] = N_EDGES;
}

__global__ void k_scatter(const int* __restrict__ src, const int* __restrict__ dst,
                          const float* __restrict__ vals, const int* __restrict__ row_ptr,
                          int* __restrict__ fill, int* __restrict__ s_src,
                          float* __restrict__ s_val) {
    int i = blockIdx.x * blockDim.x + threadIdx.x;
    int stride = gridDim.x * blockDim.x;
    for (; i < N_EDGES; i += stride) {
        int d = dst[i];
        int pos = row_ptr[d] + atomicAdd(&fill[d], 1);
        s_src[pos] = src[i];
        s_val[pos] = vals[i];
    }
}

// ---------------- SpMM: one wave per dst node ----------------
__global__ void k_spmm(const float* __restrict__ emb_in, float* __restrict__ emb_out,
                       const int* __restrict__ row_ptr, const int* __restrict__ s_src,
                       const float* __restrict__ s_val) {
    int wave = (blockIdx.x * blockDim.x + threadIdx.x) >> 6;
    if (wave >= N_NODES) return;
    int lane = threadIdx.x & 63;
    int g = lane >> 4;        // edge group 0..3
    int q = lane & 15;        // dim quad 0..15 -> dims q*4..q*4+3
    int start = row_ptr[wave], end = row_ptr[wave + 1];
    float4 acc = make_float4(0.f, 0.f, 0.f, 0.f);
    for (int e = start + g; e < end; e += 4) {
        int s = s_src[e];
        float v = s_val[e];
        const float4 x = *(const float4*)(emb_in + (size_t)s * DIM + q * 4);
        acc.x += v * x.x;
        acc.y += v * x.y;
        acc.z += v * x.z;
        acc.w += v * x.w;
    }
    // reduce across the 4 edge groups (lanes differing in bits 4,5)
    for (int off = 16; off < 64; off <<= 1) {
        acc.x += __shfl_xor(acc.x, off);
        acc.y += __shfl_xor(acc.y, off);
        acc.z += __shfl_xor(acc.z, off);
        acc.w += __shfl_xor(acc.w, off);
    }
    if (lane < 16) {
        *(float4*)(emb_out + (size_t)wave * DIM + q * 4) = acc;
    }
}

// gather sampled rows and accumulate into small acc buffers
__global__ void k_gather_acc(const float* __restrict__ emb, const int* __restrict__ idx,
                             float* __restrict__ acc, int offset) {
    int i = blockIdx.x * blockDim.x + threadIdx.x;
    if (i >= BATCH * DIM) return;
    int b = i >> 6, l = i & 63;
    acc[i] += emb[(size_t)(idx[b] + offset) * DIM + l];
}

__global__ void k_dot(const float* __restrict__ accU, const float* __restrict__ accI,
                      float* __restrict__ out) {
    int wave = (blockIdx.x * blockDim.x + threadIdx.x) >> 6;
    if (wave >= BATCH) return;
    int lane = threadIdx.x & 63;
    float p = accU[wave * 64 + lane] * accI[wave * 64 + lane];
    for (int off = 32; off; off >>= 1) p += __shfl_xor(p, off);
    if (lane == 0) out[wave] = p * (1.0f / 16.0f);  // (acc/4)·(acc/4)
}

// ---------------- launch ----------------

extern "C" void kernel_launch(void* const* d_in, const int* in_sizes, int n_in,
                              void* d_out, int out_size, void* d_ws, size_t ws_size,
                              hipStream_t stream) {
    const float* user_emb = (const float*)d_in[0];
    const float* item_emb = (const float*)d_in[1];
    const float* vals = (const float*)d_in[2];
    const int* src = (const int*)d_in[3];
    const int* dst = (const int*)d_in[4];
    const int* users = (const int*)d_in[5];
    const int* items = (const int*)d_in[6];
    float* out = (float*)d_out;

    // workspace layout (256B-aligned)
    char* ws = (char*)d_ws;
    size_t off = 0;
    auto alloc = [&](size_t bytes) {
        char* p = ws + off;
        off += (bytes + 255) & ~(size_t)255;
        return p;
    };
    float* embA = (float*)alloc((size_t)N_NODES * DIM * 4);
    float* embB = (float*)alloc((size_t)N_NODES * DIM * 4);
    int* s_src = (int*)alloc((size_t)N_EDGES * 4);
    float* s_val = (float*)alloc((size_t)N_EDGES * 4);
    int* deg = (int*)alloc((size_t)N_NODES * 4);
    int* row_ptr = (int*)alloc((size_t)(N_NODES + 1) * 4);
    int* fill = (int*)alloc((size_t)N_NODES * 4);
    int* partial = (int*)alloc((size_t)SCAN_NBLK * 4);
    float* accU = (float*)alloc((size_t)BATCH * DIM * 4);
    float* accI = (float*)alloc((size_t)BATCH * DIM * 4);

    // zero what needs zeroing
    hipMemsetAsync(deg, 0, (size_t)N_NODES * 4, stream);
    hipMemsetAsync(fill, 0, (size_t)N_NODES * 4, stream);
    hipMemsetAsync(accU, 0, (size_t)BATCH * DIM * 4, stream);
    hipMemsetAsync(accI, 0, (size_t)BATCH * DIM * 4, stream);

    // embA = concat(user_emb, item_emb)
    hipMemcpyAsync(embA, user_emb, (size_t)N_USERS * DIM * 4, hipMemcpyDeviceToDevice, stream);
    hipMemcpyAsync(embA + (size_t)N_USERS * DIM, item_emb, (size_t)N_ITEMS * DIM * 4,
                   hipMemcpyDeviceToDevice, stream);

    // CSR build
    k_hist<<<1024, 256, 0, stream>>>(dst, deg);
    k_scan1<<<SCAN_NBLK, 256, 0, stream>>>(deg, partial);
    k_scan2<<<1, 64, 0, stream>>>(partial);
    k_scan3<<<SCAN_NBLK, 256, 0, stream>>>(deg, partial, row_ptr);
    k_scatter<<<2048, 256, 0, stream>>>(src, dst, vals, row_ptr, fill, s_src, s_val);

    // layer-0 contribution to sampled accumulators
    k_gather_acc<<<(BATCH * DIM + 255) / 256, 256, 0, stream>>>(embA, users, accU, 0);
    k_gather_acc<<<(BATCH * DIM + 255) / 256, 256, 0, stream>>>(embA, items, accI, N_USERS);

    float* ein = embA;
    float* eout = embB;
    for (int layer = 0; layer < 3; layer++) {
        int nthreads = N_NODES * 64;
        k_spmm<<<(nthreads + 255) / 256, 256, 0, stream>>>(ein, eout, row_ptr, s_src, s_val);
        k_gather_acc<<<(BATCH * DIM + 255) / 256, 256, 0, stream>>>(eout, users, accU, 0);
        k_gather_acc<<<(BATCH * DIM + 255) / 256, 256, 0, stream>>>(eout, items, accI, N_USERS);
        float* t = ein; ein = eout; eout = t;
    }

    k_dot<<<(BATCH * 64 + 255) / 256, 256, 0, stream>>>(accU, accI, out);
}

// Round 2
// 679.248 us; speedup vs baseline: 1.5274x; 1.5274x over previous
//
#include <hip/hip_runtime.h>
#include <hip/hip_bf16.h>

#define N_USERS 100000
#define N_ITEMS 50000
#define N_NODES 150000
#define DIM 64
#define N_EDGES 4000000
#define BATCH 4096

#define NBKT 256
#define BW 587           // nodes per bucket; 256*587 = 150272 >= 150000
#define CAP 24           // LDS staging slots per bucket in pass A
#define PA_EDGES 4096    // edges per block in pass A

// ---------------- bucket histogram (256 bins) ----------------
__global__ void k_bhist(const int* __restrict__ dst, int* __restrict__ gh) {
    __shared__ int h[NBKT];
    int t = threadIdx.x;
    h[t] = 0;
    __syncthreads();
    int i = blockIdx.x * blockDim.x + t;
    int stride = gridDim.x * blockDim.x;
    for (; i < N_EDGES; i += stride) atomicAdd(&h[dst[i] / BW], 1);
    __syncthreads();
    if (h[t]) atomicAdd(&gh[t], h[t]);
}

// scan 256 bins -> bucket_ptr[257], init gcur
__global__ void k_bscan(const int* __restrict__ gh, int* __restrict__ bucket_ptr,
                        int* __restrict__ gcur) {
    int lane = threadIdx.x;  // 64 threads
    int carry = 0;
    for (int c = 0; c < 4; c++) {
        int i = c * 64 + lane;
        int x = gh[i];
        int incl = x;
        for (int off = 1; off < 64; off <<= 1) {
            int y = __shfl_up(incl, off);
            if (lane >= off) incl += y;
        }
        int excl = carry + incl - x;
        bucket_ptr[i] = excl;
        gcur[i] = excl;
        carry += __shfl(incl, 63);
    }
    if (lane == 0) bucket_ptr[NBKT] = N_EDGES;
}

// ---------------- pass A: LDS-staged partition into buckets ----------------
__global__ void k_partition(const int* __restrict__ src, const int* __restrict__ dst,
                            const float* __restrict__ vals, int* __restrict__ gcur,
                            int2* __restrict__ tmp) {
    __shared__ int cnt[NBKT];
    __shared__ int2 buf[NBKT][CAP];  // 48 KB
    int t = threadIdx.x;
    cnt[t] = 0;
    __syncthreads();
    size_t base = (size_t)blockIdx.x * PA_EDGES;
#pragma unroll
    for (int it = 0; it < PA_EDGES / 256; it++) {
        size_t i = base + (size_t)it * 256 + t;
        if (i < N_EDGES) {
            int d = dst[i];
            int b = d / BW;
            int local = d - b * BW;
            int2 rec = make_int2((src[i] << 10) | local, __float_as_int(vals[i]));
            int slot = atomicAdd(&cnt[b], 1);
            if (slot < CAP) buf[b][slot] = rec;
            else tmp[atomicAdd(&gcur[b], 1)] = rec;  // rare overflow path
        }
    }
    __syncthreads();
    int c = min(cnt[t], CAP);
    if (c > 0) {
        int p = atomicAdd(&gcur[t], c);
        for (int j = 0; j < c; j++) tmp[p + j] = buf[t][j];
    }
}

// ---------------- pass B: sort within bucket (LDS hist + scan), emit CSR ----------------
__global__ void k_bsort(const int2* __restrict__ tmp, const int* __restrict__ bucket_ptr,
                        int* __restrict__ row_ptr, int2* __restrict__ fin) {
    __shared__ int cnt[BW + 64];
    __shared__ int off[BW + 64];
    int b = blockIdx.x, t = threadIdx.x;  // 512 threads
    int node0 = b * BW;
    int nodes = min(BW, N_NODES - node0);
    int gbase = bucket_ptr[b], gend = bucket_ptr[b + 1];
    for (int i = t; i < BW + 64; i += 512) cnt[i] = 0;
    __syncthreads();
    for (int e = gbase + t; e < gend; e += 512) atomicAdd(&cnt[tmp[e].x & 1023], 1);
    __syncthreads();
    if (t < 64) {
        int lane = t;
        int carry = 0;
        for (int c = 0; c < 10; c++) {
            int i = c * 64 + lane;
            int x = (i < nodes) ? cnt[i] : 0;
            int incl = x;
            for (int o = 1; o < 64; o <<= 1) {
                int y = __shfl_up(incl, o);
                if (lane >= o) incl += y;
            }
            if (i <= nodes) off[i] = carry + incl - x;
            carry += __shfl(incl, 63);
        }
    }
    __syncthreads();
    for (int i = t; i <= nodes; i += 512)
        if (node0 + i <= N_NODES) row_ptr[node0 + i] = gbase + off[i];
    __syncthreads();
    for (int e = gbase + t; e < gend; e += 512) {
        int2 r = tmp[e];
        int local = r.x & 1023;
        int pos = gbase + atomicAdd(&off[local], 1);
        fin[pos] = make_int2(r.x >> 10, r.y);
    }
}

// ---------------- SpMM: one wave per dst node ----------------
__global__ void k_spmm(const float* __restrict__ emb_in, float* __restrict__ emb_out,
                       const int* __restrict__ row_ptr, const int2* __restrict__ fin) {
    int wave = (blockIdx.x * blockDim.x + threadIdx.x) >> 6;
    if (wave >= N_NODES) return;
    int lane = threadIdx.x & 63;
    int g = lane >> 4;  // edge group 0..3
    int q = lane & 15;  // dim quad
    int start = row_ptr[wave], end = row_ptr[wave + 1];
    float4 acc = make_float4(0.f, 0.f, 0.f, 0.f);
    int e = start + g;
    for (; e + 4 < end; e += 8) {
        int2 r0 = fin[e];
        int2 r1 = fin[e + 4];
        const float4 x0 = *(const float4*)(emb_in + (size_t)r0.x * DIM + q * 4);
        const float4 x1 = *(const float4*)(emb_in + (size_t)r1.x * DIM + q * 4);
        float v0 = __int_as_float(r0.y), v1 = __int_as_float(r1.y);
        acc.x += v0 * x0.x + v1 * x1.x;
        acc.y += v0 * x0.y + v1 * x1.y;
        acc.z += v0 * x0.z + v1 * x1.z;
        acc.w += v0 * x0.w + v1 * x1.w;
    }
    if (e < end) {
        int2 r0 = fin[e];
        const float4 x0 = *(const float4*)(emb_in + (size_t)r0.x * DIM + q * 4);
        float v0 = __int_as_float(r0.y);
        acc.x += v0 * x0.x;
        acc.y += v0 * x0.y;
        acc.z += v0 * x0.z;
        acc.w += v0 * x0.w;
    }
    for (int off = 16; off < 64; off <<= 1) {
        acc.x += __shfl_xor(acc.x, off);
        acc.y += __shfl_xor(acc.y, off);
        acc.z += __shfl_xor(acc.z, off);
        acc.w += __shfl_xor(acc.w, off);
    }
    if (lane < 16) *(float4*)(emb_out + (size_t)wave * DIM + q * 4) = acc;
}

__global__ void k_gather_acc(const float* __restrict__ emb, const int* __restrict__ idx,
                             float* __restrict__ acc, int offset) {
    int i = blockIdx.x * blockDim.x + threadIdx.x;
    if (i >= BATCH * DIM) return;
    int b = i >> 6, l = i & 63;
    acc[i] += emb[(size_t)(idx[b] + offset) * DIM + l];
}

__global__ void k_dot(const float* __restrict__ accU, const float* __restrict__ accI,
                      float* __restrict__ out) {
    int wave = (blockIdx.x * blockDim.x + threadIdx.x) >> 6;
    if (wave >= BATCH) return;
    int lane = threadIdx.x & 63;
    float p = accU[wave * 64 + lane] * accI[wave * 64 + lane];
    for (int off = 32; off; off >>= 1) p += __shfl_xor(p, off);
    if (lane == 0) out[wave] = p * (1.0f / 16.0f);  // (acc/4)·(acc/4)
}

// ---------------- launch ----------------

extern "C" void kernel_launch(void* const* d_in, const int* in_sizes, int n_in,
                              void* d_out, int out_size, void* d_ws, size_t ws_size,
                              hipStream_t stream) {
    const float* user_emb = (const float*)d_in[0];
    const float* item_emb = (const float*)d_in[1];
    const float* vals = (const float*)d_in[2];
    const int* src = (const int*)d_in[3];
    const int* dst = (const int*)d_in[4];
    const int* users = (const int*)d_in[5];
    const int* items = (const int*)d_in[6];
    float* out = (float*)d_out;

    char* ws = (char*)d_ws;
    size_t off = 0;
    auto alloc = [&](size_t bytes) {
        char* p = ws + off;
        off += (bytes + 255) & ~(size_t)255;
        return p;
    };
    float* embA = (float*)alloc((size_t)N_NODES * DIM * 4);
    float* embB = (float*)alloc((size_t)N_NODES * DIM * 4);  // aliases tmp (pass A/B scratch)
    int2* fin = (int2*)alloc((size_t)N_EDGES * 8);
    int* row_ptr = (int*)alloc((size_t)(N_NODES + 1) * 4);
    int* gh = (int*)alloc((size_t)NBKT * 4);
    int* bucket_ptr = (int*)alloc((size_t)(NBKT + 1) * 4);
    int* gcur = (int*)alloc((size_t)NBKT * 4);
    float* accU = (float*)alloc((size_t)BATCH * DIM * 4);
    float* accI = (float*)alloc((size_t)BATCH * DIM * 4);
    int2* tmp = (int2*)embB;  // 32 MB <= 38.4 MB, dead before embB is first written

    hipMemsetAsync(gh, 0, (size_t)NBKT * 4, stream);
    hipMemsetAsync(accU, 0, (size_t)BATCH * DIM * 4, stream);
    hipMemsetAsync(accI, 0, (size_t)BATCH * DIM * 4, stream);

    // embA = concat(user_emb, item_emb)
    hipMemcpyAsync(embA, user_emb, (size_t)N_USERS * DIM * 4, hipMemcpyDeviceToDevice, stream);
    hipMemcpyAsync(embA + (size_t)N_USERS * DIM, item_emb, (size_t)N_ITEMS * DIM * 4,
                   hipMemcpyDeviceToDevice, stream);

    // CSR build via bucket sort
    k_bhist<<<1024, NBKT, 0, stream>>>(dst, gh);
    k_bscan<<<1, 64, 0, stream>>>(gh, bucket_ptr, gcur);
    int pa_blocks = (N_EDGES + PA_EDGES - 1) / PA_EDGES;
    k_partition<<<pa_blocks, 256, 0, stream>>>(src, dst, vals, gcur, tmp);
    k_bsort<<<NBKT, 512, 0, stream>>>(tmp, bucket_ptr, row_ptr, fin);

    // layer-0 contribution
    k_gather_acc<<<(BATCH * DIM + 255) / 256, 256, 0, stream>>>(embA, users, accU, 0);
    k_gather_acc<<<(BATCH * DIM + 255) / 256, 256, 0, stream>>>(embA, items, accI, N_USERS);

    float* ein = embA;
    float* eout = embB;
    for (int layer = 0; layer < 3; layer++) {
        int nthreads = N_NODES * 64;
        k_spmm<<<(nthreads + 255) / 256, 256, 0, stream>>>(ein, eout, row_ptr, fin);
        k_gather_acc<<<(BATCH * DIM + 255) / 256, 256, 0, stream>>>(eout, users, accU, 0);
        k_gather_acc<<<(BATCH * DIM + 255) / 256, 256, 0, stream>>>(eout, items, accI, N_USERS);
        float* t = ein; ein = eout; eout = t;
    }

    k_dot<<<(BATCH * 64 + 255) / 256, 256, 0, stream>>>(accU, accI, out);
}

// Round 3
// 662.145 us; speedup vs baseline: 1.5669x; 1.0258x over previous
//
#include <hip/hip_runtime.h>
#include <hip/hip_bf16.h>

#define N_USERS 100000
#define N_ITEMS 50000
#define N_NODES 150000
#define DIM 64
#define N_EDGES 4000000
#define BATCH 4096

#define NBKT 256
#define BW 587           // nodes per bucket; 256*587 = 150272 >= 150000
#define CAP 24           // LDS staging slots per bucket in pass A
#define PA_EDGES 4096    // edges per block in pass A

// ---------------- bucket histogram (256 bins) ----------------
__global__ void k_bhist(const int* __restrict__ dst, int* __restrict__ gh) {
    __shared__ int h[NBKT];
    int t = threadIdx.x;
    h[t] = 0;
    __syncthreads();
    int i = blockIdx.x * blockDim.x + t;
    int stride = gridDim.x * blockDim.x;
    for (; i < N_EDGES; i += stride) atomicAdd(&h[dst[i] / BW], 1);
    __syncthreads();
    if (h[t]) atomicAdd(&gh[t], h[t]);
}

// scan 256 bins -> bucket_ptr[257], init gcur
__global__ void k_bscan(const int* __restrict__ gh, int* __restrict__ bucket_ptr,
                        int* __restrict__ gcur) {
    int lane = threadIdx.x;  // 64 threads
    int carry = 0;
    for (int c = 0; c < 4; c++) {
        int i = c * 64 + lane;
        int x = gh[i];
        int incl = x;
        for (int off = 1; off < 64; off <<= 1) {
            int y = __shfl_up(incl, off);
            if (lane >= off) incl += y;
        }
        int excl = carry + incl - x;
        bucket_ptr[i] = excl;
        gcur[i] = excl;
        carry += __shfl(incl, 63);
    }
    if (lane == 0) bucket_ptr[NBKT] = N_EDGES;
}

// ---------------- pass A: LDS-staged partition into buckets ----------------
__global__ void k_partition(const int* __restrict__ src, const int* __restrict__ dst,
                            const float* __restrict__ vals, int* __restrict__ gcur,
                            int2* __restrict__ tmp) {
    __shared__ int cnt[NBKT];
    __shared__ int2 buf[NBKT][CAP];  // 48 KB
    __shared__ int gbase_s[NBKT];
    __shared__ int pfx[NBKT + 1];
    __shared__ int wsum[4];
    int t = threadIdx.x;
    cnt[t] = 0;
    __syncthreads();
    size_t base = (size_t)blockIdx.x * PA_EDGES;
#pragma unroll
    for (int it = 0; it < PA_EDGES / 256; it++) {
        size_t i = base + (size_t)it * 256 + t;
        if (i < N_EDGES) {
            int d = dst[i];
            int b = d / BW;
            int local = d - b * BW;
            int2 rec = make_int2((src[i] << 10) | local, __float_as_int(vals[i]));
            int slot = atomicAdd(&cnt[b], 1);
            if (slot < CAP) buf[b][slot] = rec;
            else tmp[atomicAdd(&gcur[b], 1)] = rec;  // rare overflow path
        }
    }
    __syncthreads();
    // cooperative drain: per-bin global base + LDS prefix over capped counts
    int c = min(cnt[t], CAP);
    int p = (c > 0) ? atomicAdd(&gcur[t], c) : 0;
    gbase_s[t] = p;
    int lane = t & 63, w = t >> 6;
    int incl = c;
    for (int o = 1; o < 64; o <<= 1) {
        int y = __shfl_up(incl, o);
        if (lane >= o) incl += y;
    }
    if (lane == 63) wsum[w] = incl;
    __syncthreads();
    int woff = 0;
    for (int j = 0; j < w; j++) woff += wsum[j];
    int excl = woff + incl - c;
    pfx[t] = excl;
    if (t == 255) pfx[256] = excl + c;
    __syncthreads();
    int total = pfx[256];
    for (int f = t; f < total; f += 256) {
        int lo = 0, hi = 255;
        while (lo < hi) {  // largest bin with pfx[bin] <= f
            int mid = (lo + hi + 1) >> 1;
            if (pfx[mid] <= f) lo = mid; else hi = mid - 1;
        }
        int slot = f - pfx[lo];
        tmp[gbase_s[lo] + slot] = buf[lo][slot];
    }
}

// ---------------- pass B: sort within bucket (LDS hist + scan), emit CSR ----------------
__global__ void k_bsort(const int2* __restrict__ tmp, const int* __restrict__ bucket_ptr,
                        int* __restrict__ row_ptr, int2* __restrict__ fin) {
    __shared__ int cnt[BW + 64];
    __shared__ int off[BW + 64];
    int b = blockIdx.x, t = threadIdx.x;  // 512 threads
    int node0 = b * BW;
    int nodes = min(BW, N_NODES - node0);
    int gbase = bucket_ptr[b], gend = bucket_ptr[b + 1];
    for (int i = t; i < BW + 64; i += 512) cnt[i] = 0;
    __syncthreads();
    for (int e = gbase + t; e < gend; e += 512) atomicAdd(&cnt[tmp[e].x & 1023], 1);
    __syncthreads();
    if (t < 64) {
        int lane = t;
        int carry = 0;
        for (int c = 0; c < 10; c++) {
            int i = c * 64 + lane;
            int x = (i < nodes) ? cnt[i] : 0;
            int incl = x;
            for (int o = 1; o < 64; o <<= 1) {
                int y = __shfl_up(incl, o);
                if (lane >= o) incl += y;
            }
            if (i <= nodes) off[i] = carry + incl - x;
            carry += __shfl(incl, 63);
        }
    }
    __syncthreads();
    for (int i = t; i <= nodes; i += 512)
        if (node0 + i <= N_NODES) row_ptr[node0 + i] = gbase + off[i];
    __syncthreads();
    for (int e = gbase + t; e < gend; e += 512) {
        int2 r = tmp[e];
        int local = r.x & 1023;
        int pos = gbase + atomicAdd(&off[local], 1);
        fin[pos] = make_int2(r.x >> 10, r.y);
    }
}

// ---------------- SpMM: one wave per dst node, 4-deep gather pipeline ----------------
__device__ __forceinline__ const float* row_ptr_sel(const float* u, const float* i, int s) {
    return (s < N_USERS) ? (u + (size_t)s * DIM) : (i + (size_t)(s - N_USERS) * DIM);
}

__global__ void k_spmm(const float* __restrict__ uemb, const float* __restrict__ iemb,
                       float* __restrict__ emb_out,
                       const int* __restrict__ row_ptr, const int2* __restrict__ fin) {
    int wave = (blockIdx.x * blockDim.x + threadIdx.x) >> 6;
    if (wave >= N_NODES) return;
    int lane = threadIdx.x & 63;
    int g = lane >> 4;  // edge group 0..3
    int q = lane & 15;  // dim quad
    int start = row_ptr[wave], end = row_ptr[wave + 1];
    float4 acc = make_float4(0.f, 0.f, 0.f, 0.f);
    int e = start + g;
    for (; e + 12 < end; e += 16) {  // 4 edges per group in flight
        int2 r0 = fin[e];
        int2 r1 = fin[e + 4];
        int2 r2 = fin[e + 8];
        int2 r3 = fin[e + 12];
        const float4 x0 = *(const float4*)(row_ptr_sel(uemb, iemb, r0.x) + q * 4);
        const float4 x1 = *(const float4*)(row_ptr_sel(uemb, iemb, r1.x) + q * 4);
        const float4 x2 = *(const float4*)(row_ptr_sel(uemb, iemb, r2.x) + q * 4);
        const float4 x3 = *(const float4*)(row_ptr_sel(uemb, iemb, r3.x) + q * 4);
        float v0 = __int_as_float(r0.y), v1 = __int_as_float(r1.y);
        float v2 = __int_as_float(r2.y), v3 = __int_as_float(r3.y);
        acc.x += v0 * x0.x + v1 * x1.x + v2 * x2.x + v3 * x3.x;
        acc.y += v0 * x0.y + v1 * x1.y + v2 * x2.y + v3 * x3.y;
        acc.z += v0 * x0.z + v1 * x1.z + v2 * x2.z + v3 * x3.z;
        acc.w += v0 * x0.w + v1 * x1.w + v2 * x2.w + v3 * x3.w;
    }
    for (; e < end; e += 4) {
        int2 r0 = fin[e];
        const float4 x0 = *(const float4*)(row_ptr_sel(uemb, iemb, r0.x) + q * 4);
        float v0 = __int_as_float(r0.y);
        acc.x += v0 * x0.x;
        acc.y += v0 * x0.y;
        acc.z += v0 * x0.z;
        acc.w += v0 * x0.w;
    }
    for (int off = 16; off < 64; off <<= 1) {
        acc.x += __shfl_xor(acc.x, off);
        acc.y += __shfl_xor(acc.y, off);
        acc.z += __shfl_xor(acc.z, off);
        acc.w += __shfl_xor(acc.w, off);
    }
    if (lane < 16) *(float4*)(emb_out + (size_t)wave * DIM + q * 4) = acc;
}

// layer-0: overwrite (acc buffers are poisoned, not zeroed)
__global__ void k_gather0(const float* __restrict__ emb, const int* __restrict__ idx,
                          float* __restrict__ acc) {
    int i = blockIdx.x * blockDim.x + threadIdx.x;
    if (i >= BATCH * DIM) return;
    int b = i >> 6, l = i & 63;
    acc[i] = emb[(size_t)idx[b] * DIM + l];
}

__global__ void k_gather_acc(const float* __restrict__ emb, const int* __restrict__ idx,
                             float* __restrict__ acc, int offset) {
    int i = blockIdx.x * blockDim.x + threadIdx.x;
    if (i >= BATCH * DIM) return;
    int b = i >> 6, l = i & 63;
    acc[i] += emb[(size_t)(idx[b] + offset) * DIM + l];
}

__global__ void k_dot(const float* __restrict__ accU, const float* __restrict__ accI,
                      float* __restrict__ out) {
    int wave = (blockIdx.x * blockDim.x + threadIdx.x) >> 6;
    if (wave >= BATCH) return;
    int lane = threadIdx.x & 63;
    float p = accU[wave * 64 + lane] * accI[wave * 64 + lane];
    for (int off = 32; off; off >>= 1) p += __shfl_xor(p, off);
    if (lane == 0) out[wave] = p * (1.0f / 16.0f);  // (acc/4)·(acc/4)
}

// ---------------- launch ----------------

extern "C" void kernel_launch(void* const* d_in, const int* in_sizes, int n_in,
                              void* d_out, int out_size, void* d_ws, size_t ws_size,
                              hipStream_t stream) {
    const float* user_emb = (const float*)d_in[0];
    const float* item_emb = (const float*)d_in[1];
    const float* vals = (const float*)d_in[2];
    const int* src = (const int*)d_in[3];
    const int* dst = (const int*)d_in[4];
    const int* users = (const int*)d_in[5];
    const int* items = (const int*)d_in[6];
    float* out = (float*)d_out;

    char* ws = (char*)d_ws;
    size_t off = 0;
    auto alloc = [&](size_t bytes) {
        char* p = ws + off;
        off += (bytes + 255) & ~(size_t)255;
        return p;
    };
    float* bufA = (float*)alloc((size_t)N_NODES * DIM * 4);
    float* bufB = (float*)alloc((size_t)N_NODES * DIM * 4);
    int2* fin = (int2*)alloc((size_t)N_EDGES * 8);
    int* row_ptr = (int*)alloc((size_t)(N_NODES + 1) * 4);
    int* gh = (int*)alloc((size_t)NBKT * 4);
    int* bucket_ptr = (int*)alloc((size_t)(NBKT + 1) * 4);
    int* gcur = (int*)alloc((size_t)NBKT * 4);
    float* accU = (float*)alloc((size_t)BATCH * DIM * 4);
    float* accI = (float*)alloc((size_t)BATCH * DIM * 4);
    int2* tmp = (int2*)bufA;  // 32 MB scratch; dead before bufA is first written (layer 2)

    hipMemsetAsync(gh, 0, (size_t)NBKT * 4, stream);

    // CSR build via bucket sort
    k_bhist<<<1024, NBKT, 0, stream>>>(dst, gh);
    k_bscan<<<1, 64, 0, stream>>>(gh, bucket_ptr, gcur);
    int pa_blocks = (N_EDGES + PA_EDGES - 1) / PA_EDGES;
    k_partition<<<pa_blocks, 256, 0, stream>>>(src, dst, vals, gcur, tmp);
    k_bsort<<<NBKT, 512, 0, stream>>>(tmp, bucket_ptr, row_ptr, fin);

    // layer-0 contribution straight from the input tables (no concat copy)
    k_gather0<<<(BATCH * DIM + 255) / 256, 256, 0, stream>>>(user_emb, users, accU);
    k_gather0<<<(BATCH * DIM + 255) / 256, 256, 0, stream>>>(item_emb, items, accI);

    int nthreads = N_NODES * 64;
    int spmm_blocks = (nthreads + 255) / 256;
    // layer 1: read split input tables, write bufB
    k_spmm<<<spmm_blocks, 256, 0, stream>>>(user_emb, item_emb, bufB, row_ptr, fin);
    k_gather_acc<<<(BATCH * DIM + 255) / 256, 256, 0, stream>>>(bufB, users, accU, 0);
    k_gather_acc<<<(BATCH * DIM + 255) / 256, 256, 0, stream>>>(bufB, items, accI, N_USERS);
    // layer 2: bufB -> bufA
    k_spmm<<<spmm_blocks, 256, 0, stream>>>(bufB, bufB + (size_t)N_USERS * DIM, bufA, row_ptr, fin);
    k_gather_acc<<<(BATCH * DIM + 255) / 256, 256, 0, stream>>>(bufA, users, accU, 0);
    k_gather_acc<<<(BATCH * DIM + 255) / 256, 256, 0, stream>>>(bufA, items, accI, N_USERS);
    // layer 3: bufA -> bufB
    k_spmm<<<spmm_blocks, 256, 0, stream>>>(bufA, bufA + (size_t)N_USERS * DIM, bufB, row_ptr, fin);
    k_gather_acc<<<(BATCH * DIM + 255) / 256, 256, 0, stream>>>(bufB, users, accU, 0);
    k_gather_acc<<<(BATCH * DIM + 255) / 256, 256, 0, stream>>>(bufB, items, accI, N_USERS);

    k_dot<<<(BATCH * 64 + 255) / 256, 256, 0, stream>>>(accU, accI, out);
}

// Round 4
// 426.911 us; speedup vs baseline: 2.4303x; 1.5510x over previous
//
#include <hip/hip_runtime.h>
#include <hip/hip_bf16.h>

#define N_USERS 100000
#define N_ITEMS 50000
#define N_NODES 150000
#define DIM 64
#define N_EDGES 4000000
#define BATCH 4096

#define NBKT 256
#define BW 587           // nodes per bucket; 256*587 = 150272 >= 150000
#define CAP 24           // LDS staging slots per bucket in pass A
#define PA_EDGES 4096    // edges per block in pass A

// ---------------- bf16 helpers ----------------
__device__ __forceinline__ float blo(unsigned int u) { return __uint_as_float(u << 16); }
__device__ __forceinline__ float bhi(unsigned int u) { return __uint_as_float(u & 0xffff0000u); }
__device__ __forceinline__ unsigned int f2b(float f) {  // RTNE
    unsigned int x = __float_as_uint(f);
    return (x + 0x7fffu + ((x >> 16) & 1u)) >> 16;
}
__device__ __forceinline__ unsigned int pack2(float a, float b) {
    return f2b(a) | (f2b(b) << 16);
}

// fp32 table -> bf16 table
__global__ void k_cvt(const float* __restrict__ in, ushort* __restrict__ out, int n) {
    int i = (blockIdx.x * blockDim.x + threadIdx.x) * 4;
    if (i >= n) return;
    float4 v = *(const float4*)(in + i);
    uint2 p = make_uint2(pack2(v.x, v.y), pack2(v.z, v.w));
    *(uint2*)(out + i) = p;
}

// ---------------- bucket histogram (256 bins) ----------------
__global__ void k_bhist(const int* __restrict__ dst, int* __restrict__ gh) {
    __shared__ int h[NBKT];
    int t = threadIdx.x;
    h[t] = 0;
    __syncthreads();
    int i = blockIdx.x * blockDim.x + t;
    int stride = gridDim.x * blockDim.x;
    for (; i < N_EDGES; i += stride) atomicAdd(&h[dst[i] / BW], 1);
    __syncthreads();
    if (h[t]) atomicAdd(&gh[t], h[t]);
}

// scan 256 bins -> bucket_ptr[257], init gcur
__global__ void k_bscan(const int* __restrict__ gh, int* __restrict__ bucket_ptr,
                        int* __restrict__ gcur) {
    int lane = threadIdx.x;  // 64 threads
    int carry = 0;
    for (int c = 0; c < 4; c++) {
        int i = c * 64 + lane;
        int x = gh[i];
        int incl = x;
        for (int off = 1; off < 64; off <<= 1) {
            int y = __shfl_up(incl, off);
            if (lane >= off) incl += y;
        }
        int excl = carry + incl - x;
        bucket_ptr[i] = excl;
        gcur[i] = excl;
        carry += __shfl(incl, 63);
    }
    if (lane == 0) bucket_ptr[NBKT] = N_EDGES;
}

// ---------------- pass A: LDS-staged partition into buckets ----------------
__global__ void k_partition(const int* __restrict__ src, const int* __restrict__ dst,
                            const float* __restrict__ vals, int* __restrict__ gcur,
                            int2* __restrict__ tmp) {
    __shared__ int cnt[NBKT];
    __shared__ int2 buf[NBKT][CAP];  // 48 KB
    __shared__ int gbase_s[NBKT];
    __shared__ int pfx[NBKT + 1];
    __shared__ int wsum[4];
    int t = threadIdx.x;
    cnt[t] = 0;
    __syncthreads();
    size_t base = (size_t)blockIdx.x * PA_EDGES;
#pragma unroll
    for (int it = 0; it < PA_EDGES / 256; it++) {
        size_t i = base + (size_t)it * 256 + t;
        if (i < N_EDGES) {
            int d = dst[i];
            int b = d / BW;
            int local = d - b * BW;
            int2 rec = make_int2((src[i] << 10) | local, __float_as_int(vals[i]));
            int slot = atomicAdd(&cnt[b], 1);
            if (slot < CAP) buf[b][slot] = rec;
            else tmp[atomicAdd(&gcur[b], 1)] = rec;  // rare overflow path
        }
    }
    __syncthreads();
    // cooperative drain: per-bin global base + LDS prefix over capped counts
    int c = min(cnt[t], CAP);
    int p = (c > 0) ? atomicAdd(&gcur[t], c) : 0;
    gbase_s[t] = p;
    int lane = t & 63, w = t >> 6;
    int incl = c;
    for (int o = 1; o < 64; o <<= 1) {
        int y = __shfl_up(incl, o);
        if (lane >= o) incl += y;
    }
    if (lane == 63) wsum[w] = incl;
    __syncthreads();
    int woff = 0;
    for (int j = 0; j < w; j++) woff += wsum[j];
    int excl = woff + incl - c;
    pfx[t] = excl;
    if (t == 255) pfx[256] = excl + c;
    __syncthreads();
    int total = pfx[256];
    for (int f = t; f < total; f += 256) {
        int lo = 0, hi = 255;
        while (lo < hi) {  // largest bin with pfx[bin] <= f
            int mid = (lo + hi + 1) >> 1;
            if (pfx[mid] <= f) lo = mid; else hi = mid - 1;
        }
        int slot = f - pfx[lo];
        tmp[gbase_s[lo] + slot] = buf[lo][slot];
    }
}

// ---------------- pass B: sort within bucket (LDS hist + scan), emit CSR ----------------
__global__ void k_bsort(const int2* __restrict__ tmp, const int* __restrict__ bucket_ptr,
                        int* __restrict__ row_ptr, int2* __restrict__ fin) {
    __shared__ int cnt[BW + 64];
    __shared__ int off[BW + 64];
    int b = blockIdx.x, t = threadIdx.x;  // 512 threads
    int node0 = b * BW;
    int nodes = min(BW, N_NODES - node0);
    int gbase = bucket_ptr[b], gend = bucket_ptr[b + 1];
    for (int i = t; i < BW + 64; i += 512) cnt[i] = 0;
    __syncthreads();
    for (int e = gbase + t; e < gend; e += 512) atomicAdd(&cnt[tmp[e].x & 1023], 1);
    __syncthreads();
    if (t < 64) {
        int lane = t;
        int carry = 0;
        for (int c = 0; c < 10; c++) {
            int i = c * 64 + lane;
            int x = (i < nodes) ? cnt[i] : 0;
            int incl = x;
            for (int o = 1; o < 64; o <<= 1) {
                int y = __shfl_up(incl, o);
                if (lane >= o) incl += y;
            }
            if (i <= nodes) off[i] = carry + incl - x;
            carry += __shfl(incl, 63);
        }
    }
    __syncthreads();
    for (int i = t; i <= nodes; i += 512)
        if (node0 + i <= N_NODES) row_ptr[node0 + i] = gbase + off[i];
    __syncthreads();
    for (int e = gbase + t; e < gend; e += 512) {
        int2 r = tmp[e];
        int local = r.x & 1023;
        int pos = gbase + atomicAdd(&off[local], 1);
        fin[pos] = make_int2(r.x >> 10, r.y);
    }
}

// ---------------- bf16 SpMM: one wave per dst node, 8 groups x 8 lanes ----------------
#define SPMM_EDGE(r)                                                              \
    {                                                                             \
        const uint4 u = *(const uint4*)(ein + (size_t)(r).x * DIM + q * 8);       \
        float v = __int_as_float((r).y);                                          \
        acc[0] += v * blo(u.x); acc[1] += v * bhi(u.x);                           \
        acc[2] += v * blo(u.y); acc[3] += v * bhi(u.y);                           \
        acc[4] += v * blo(u.z); acc[5] += v * bhi(u.z);                           \
        acc[6] += v * blo(u.w); acc[7] += v * bhi(u.w);                           \
    }

__global__ void k_spmm16(const ushort* __restrict__ ein, ushort* __restrict__ eout,
                         const int* __restrict__ row_ptr, const int2* __restrict__ fin) {
    int wave = (blockIdx.x * blockDim.x + threadIdx.x) >> 6;
    if (wave >= N_NODES) return;
    int lane = threadIdx.x & 63;
    int g = lane >> 3;  // edge group 0..7
    int q = lane & 7;   // 8 bf16 dims per lane
    int start = row_ptr[wave], end = row_ptr[wave + 1];
    float acc[8];
#pragma unroll
    for (int j = 0; j < 8; j++) acc[j] = 0.f;
    int e = start + g;
    for (; e + 8 < end; e += 16) {
        int2 r0 = fin[e];
        int2 r1 = fin[e + 8];
        SPMM_EDGE(r0);
        SPMM_EDGE(r1);
    }
    for (; e < end; e += 8) {
        int2 r0 = fin[e];
        SPMM_EDGE(r0);
    }
#pragma unroll
    for (int off = 8; off < 64; off <<= 1) {
#pragma unroll
        for (int j = 0; j < 8; j++) acc[j] += __shfl_xor(acc[j], off);
    }
    if (lane < 8) {
        uint4 p;
        p.x = pack2(acc[0], acc[1]);
        p.y = pack2(acc[2], acc[3]);
        p.z = pack2(acc[4], acc[5]);
        p.w = pack2(acc[6], acc[7]);
        *(uint4*)(eout + (size_t)wave * DIM + q * 8) = p;
    }
}

// layer-3: SpMM only at sampled rows, accumulate fp32 into acc
__global__ void k_spmm_samp(const ushort* __restrict__ ein, const int* __restrict__ idx,
                            int offset, const int* __restrict__ row_ptr,
                            const int2* __restrict__ fin, float* __restrict__ accb) {
    int wv = (blockIdx.x * blockDim.x + threadIdx.x) >> 6;
    if (wv >= BATCH) return;
    int lane = threadIdx.x & 63;
    int g = lane >> 3;
    int q = lane & 7;
    int node = idx[wv] + offset;
    int start = row_ptr[node], end = row_ptr[node + 1];
    float acc[8];
#pragma unroll
    for (int j = 0; j < 8; j++) acc[j] = 0.f;
    for (int e = start + g; e < end; e += 8) {
        int2 r0 = fin[e];
        SPMM_EDGE(r0);
    }
#pragma unroll
    for (int off = 8; off < 64; off <<= 1) {
#pragma unroll
        for (int j = 0; j < 8; j++) acc[j] += __shfl_xor(acc[j], off);
    }
    if (lane < 8) {
        float* row = accb + (size_t)wv * DIM + q * 8;
        float4 a0 = *(float4*)row;
        float4 a1 = *(float4*)(row + 4);
        a0.x += acc[0]; a0.y += acc[1]; a0.z += acc[2]; a0.w += acc[3];
        a1.x += acc[4]; a1.y += acc[5]; a1.z += acc[6]; a1.w += acc[7];
        *(float4*)row = a0;
        *(float4*)(row + 4) = a1;
    }
}

// layer-0: overwrite from fp32 input tables (acc buffers are poisoned, not zeroed)
__global__ void k_gather0(const float* __restrict__ emb, const int* __restrict__ idx,
                          float* __restrict__ acc) {
    int i = blockIdx.x * blockDim.x + threadIdx.x;
    if (i >= BATCH * DIM) return;
    int b = i >> 6, l = i & 63;
    acc[i] = emb[(size_t)idx[b] * DIM + l];
}

// layers 1-2: accumulate from bf16 tables
__global__ void k_gather_acc16(const ushort* __restrict__ emb, const int* __restrict__ idx,
                               float* __restrict__ acc, int offset) {
    int i = blockIdx.x * blockDim.x + threadIdx.x;
    if (i >= BATCH * DIM) return;
    int b = i >> 6, l = i & 63;
    unsigned int u = emb[(size_t)(idx[b] + offset) * DIM + l];
    acc[i] += __uint_as_float(u << 16);
}

__global__ void k_dot(const float* __restrict__ accU, const float* __restrict__ accI,
                      float* __restrict__ out) {
    int wave = (blockIdx.x * blockDim.x + threadIdx.x) >> 6;
    if (wave >= BATCH) return;
    int lane = threadIdx.x & 63;
    float p = accU[wave * 64 + lane] * accI[wave * 64 + lane];
    for (int off = 32; off; off >>= 1) p += __shfl_xor(p, off);
    if (lane == 0) out[wave] = p * (1.0f / 16.0f);  // (acc/4)·(acc/4)
}

// ---------------- launch ----------------

extern "C" void kernel_launch(void* const* d_in, const int* in_sizes, int n_in,
                              void* d_out, int out_size, void* d_ws, size_t ws_size,
                              hipStream_t stream) {
    const float* user_emb = (const float*)d_in[0];
    const float* item_emb = (const float*)d_in[1];
    const float* vals = (const float*)d_in[2];
    const int* src = (const int*)d_in[3];
    const int* dst = (const int*)d_in[4];
    const int* users = (const int*)d_in[5];
    const int* items = (const int*)d_in[6];
    float* out = (float*)d_out;

    char* ws = (char*)d_ws;
    size_t off = 0;
    auto alloc = [&](size_t bytes) {
        char* p = ws + off;
        off += (bytes + 255) & ~(size_t)255;
        return p;
    };
    ushort* ebf0 = (ushort*)alloc((size_t)N_NODES * DIM * 2);  // bf16 concat(input tables)
    ushort* ebf1 = (ushort*)alloc((size_t)N_NODES * DIM * 2);  // layer-1 out (aliases tmp lo)
    ushort* ebf2 = (ushort*)alloc((size_t)N_NODES * DIM * 2);  // layer-2 out (aliases tmp hi)
    int2* fin = (int2*)alloc((size_t)N_EDGES * 8);
    int* row_ptr = (int*)alloc((size_t)(N_NODES + 1) * 4);
    int* gh = (int*)alloc((size_t)NBKT * 4);
    int* bucket_ptr = (int*)alloc((size_t)(NBKT + 1) * 4);
    int* gcur = (int*)alloc((size_t)NBKT * 4);
    float* accU = (float*)alloc((size_t)BATCH * DIM * 4);
    float* accI = (float*)alloc((size_t)BATCH * DIM * 4);
    // 32 MB partition scratch aliases ebf1+ebf2 (38.4 MB contiguous, both regions
    // are 256B-multiples); tmp is dead after k_bsort, before ebf1/2 first write.
    int2* tmp = (int2*)ebf1;

    hipMemsetAsync(gh, 0, (size_t)NBKT * 4, stream);

    // convert input tables to bf16 (concat layout)
    k_cvt<<<(N_USERS * DIM / 4 + 255) / 256, 256, 0, stream>>>(user_emb, ebf0, N_USERS * DIM);
    k_cvt<<<(N_ITEMS * DIM / 4 + 255) / 256, 256, 0, stream>>>(item_emb, ebf0 + (size_t)N_USERS * DIM,
                                                               N_ITEMS * DIM);

    // CSR build via bucket sort
    k_bhist<<<1024, NBKT, 0, stream>>>(dst, gh);
    k_bscan<<<1, 64, 0, stream>>>(gh, bucket_ptr, gcur);
    int pa_blocks = (N_EDGES + PA_EDGES - 1) / PA_EDGES;
    k_partition<<<pa_blocks, 256, 0, stream>>>(src, dst, vals, gcur, tmp);
    k_bsort<<<NBKT, 512, 0, stream>>>(tmp, bucket_ptr, row_ptr, fin);

    // layer-0 contribution straight from the fp32 input tables
    k_gather0<<<(BATCH * DIM + 255) / 256, 256, 0, stream>>>(user_emb, users, accU);
    k_gather0<<<(BATCH * DIM + 255) / 256, 256, 0, stream>>>(item_emb, items, accI);

    int spmm_blocks = (N_NODES * 64 + 255) / 256;
    int gb = (BATCH * DIM + 255) / 256;
    // layer 1: ebf0 -> ebf1
    k_spmm16<<<spmm_blocks, 256, 0, stream>>>(ebf0, ebf1, row_ptr, fin);
    k_gather_acc16<<<gb, 256, 0, stream>>>(ebf1, users, accU, 0);
    k_gather_acc16<<<gb, 256, 0, stream>>>(ebf1, items, accI, N_USERS);
    // layer 2: ebf1 -> ebf2
    k_spmm16<<<spmm_blocks, 256, 0, stream>>>(ebf1, ebf2, row_ptr, fin);
    k_gather_acc16<<<gb, 256, 0, stream>>>(ebf2, users, accU, 0);
    k_gather_acc16<<<gb, 256, 0, stream>>>(ebf2, items, accI, N_USERS);
    // layer 3: only at sampled rows, straight into acc
    k_spmm_samp<<<(BATCH * 64 + 255) / 256, 256, 0, stream>>>(ebf2, users, 0, row_ptr, fin, accU);
    k_spmm_samp<<<(BATCH * 64 + 255) / 256, 256, 0, stream>>>(ebf2, items, N_USERS, row_ptr, fin, accI);

    k_dot<<<(BATCH * 64 + 255) / 256, 256, 0, stream>>>(accU, accI, out);
}